// Round 5
// baseline (159.434 us; speedup 1.0000x reference)
//
#include <hip/hip_runtime.h>
#include <hip/hip_bf16.h>

typedef short bf16x8 __attribute__((ext_vector_type(8)));
typedef float f32x4 __attribute__((ext_vector_type(4)));

#define T_DIM 2048
#define D_DIM 64
#define WIN 128
#define QBLK 64
#define NEGBIG -1e30f

__device__ __forceinline__ short f2b(float x) {
  __hip_bfloat16 h = __float2bfloat16(x);
  return *reinterpret_cast<short*>(&h);
}
__device__ __forceinline__ float b2f(short s) {
  unsigned u = ((unsigned)(unsigned short)s) << 16;
  return __builtin_bit_cast(float, u);
}
__device__ __forceinline__ bf16x8 cvt8(f32x4 a, f32x4 b) {
  bf16x8 r;
  r[0] = f2b(a[0]); r[1] = f2b(a[1]); r[2] = f2b(a[2]); r[3] = f2b(a[3]);
  r[4] = f2b(b[0]); r[5] = f2b(b[1]); r[6] = f2b(b[2]); r[7] = f2b(b[3]);
  return r;
}
// swizzled byte address inside Vt tile, 640B rows
__device__ __forceinline__ int swzV(int row, int b) { return row * 640 + (b ^ ((row & 7) << 4)); }

#define KADDR(kt) (kptr + (size_t)(kstart + (kt) * 16 + c) * D_DIM + 8 * hi)
#define LD4(kr, d0, d1, d2, d3) do { \
  d0 = *(const f32x4*)(kr); d1 = *(const f32x4*)((kr) + 4); \
  d2 = *(const f32x4*)((kr) + 32); d3 = *(const f32x4*)((kr) + 36); } while (0)

__global__ __launch_bounds__(512, 4) void lsa_one(
    const float* __restrict__ Qg, const float* __restrict__ Kg,
    const float* __restrict__ Vg, float* __restrict__ Og,
    float* __restrict__ Ag) {
  const int tid = threadIdx.x;
  // XCD-chunked swizzle: XCD x hosts works [128x,128x+128) = 4 bh, 32 q-blocks
  const int work = ((blockIdx.x & 7) << 7) + (blockIdx.x >> 3);
  const int bh = work >> 5;
  const int q0 = (work & 31) * QBLK;
  int kstart = q0 - WIN; if (kstart < 0) kstart = 0;
  int kend = q0 + QBLK + WIN; if (kend > T_DIM) kend = T_DIM;
  const int KW = kend - kstart;   // 192/256/320, multiple of 32
  const int nkt = KW >> 4;
  const int ns = KW >> 5;

  const float* vptr = Vg + (size_t)bh * (T_DIM * D_DIM);
  float* aptr = Ag + (size_t)bh * ((size_t)T_DIM * T_DIM);

  // LDS: Vt 40KB + P staging 4KB -> with 512-thr blocks, 2 blocks/CU
  __shared__ __align__(16) char Vb[D_DIM * 640];
  __shared__ __align__(16) char Pb[4 * 1024];

  // ---- stage V transposed: Vt[d][k] bf16 (all 8 waves) ----
  for (int idx = tid; idx < KW * 16; idx += 512) {
    const int r = idx >> 4, c4 = idx & 15;
    f32x4 f = *(const f32x4*)(vptr + (size_t)(kstart + r) * D_DIM + c4 * 4);
    const int d0 = c4 * 4;
    *(short*)(Vb + swzV(d0 + 0, r * 2)) = f2b(f[0]);
    *(short*)(Vb + swzV(d0 + 1, r * 2)) = f2b(f[1]);
    *(short*)(Vb + swzV(d0 + 2, r * 2)) = f2b(f[2]);
    *(short*)(Vb + swzV(d0 + 3, r * 2)) = f2b(f[3]);
  }
  __syncthreads();   // the only barrier; executed once by every wave

  if (tid >= 256) {
    // ---- fill waves 4..7: pure streaming zeros, no further deps ----
    const int t2 = tid - 256;
    const int Lw = kstart;
    const int zn = Lw + (T_DIM - kend);      // zero floats per row
    const f32x4 z = {0.f, 0.f, 0.f, 0.f};
    float* arow = aptr + (size_t)q0 * T_DIM;
    for (int r = 0; r < QBLK; ++r, arow += T_DIM) {
      for (int cc = t2 * 4; cc < zn; cc += 1024) {
        const int col = (cc < Lw) ? cc : (kend + cc - Lw);
        __builtin_nontemporal_store(z, (f32x4*)(arow + col));
      }
    }
    return;
  }

  // ---- compute waves 0..3 ----
  const int lane = tid & 63, w = tid >> 6, c = lane & 15, hi = lane >> 4;
  const float* qptr = Qg + (size_t)bh * (T_DIM * D_DIM);
  const float* kptr = Kg + (size_t)bh * (T_DIM * D_DIM);
  float* optr = Og + (size_t)bh * (T_DIM * D_DIM);

  const float* qrow = qptr + (size_t)(q0 + w * 16 + c) * D_DIM + 8 * hi;
  const bf16x8 a0 = cvt8(*(const f32x4*)qrow, *(const f32x4*)(qrow + 4));
  const bf16x8 a1 = cvt8(*(const f32x4*)(qrow + 32), *(const f32x4*)(qrow + 36));

  // per-wave live k-tile range (mask makes any extra tile a no-op)
  int klo = q0 + w * 16 - WIN - kstart; if (klo < 0) klo = 0;
  const int kt0 = klo >> 4;
  int kt1 = (q0 + w * 16 + 15 + WIN + 1 - kstart + 15) >> 4; if (kt1 > nkt) kt1 = nkt;
  const int s0 = kt0 >> 1, s1 = (kt1 + 1) >> 1;

  // ---- pass A: online (m,l), 1-deep K prefetch ----
  f32x4 p0, p1, p2, p3;
  { const float* kr = KADDR(kt0); LD4(kr, p0, p1, p2, p3); }
  float m[4] = {NEGBIG, NEGBIG, NEGBIG, NEGBIG};
  float l[4] = {0.f, 0.f, 0.f, 0.f};
  for (int kt = kt0; kt < kt1; ++kt) {
    f32x4 n0 = p0, n1 = p1, n2 = p2, n3 = p3;
    if (kt + 1 < kt1) { const float* kr = KADDR(kt + 1); LD4(kr, n0, n1, n2, n3); }
    const bf16x8 b0 = cvt8(p0, p1), b1 = cvt8(p2, p3);
    f32x4 acc = {0.f, 0.f, 0.f, 0.f};
    acc = __builtin_amdgcn_mfma_f32_16x16x32_bf16(a0, b0, acc, 0, 0, 0);
    acc = __builtin_amdgcn_mfma_f32_16x16x32_bf16(a1, b1, acc, 0, 0, 0);
    const int kcol = kstart + kt * 16 + c;
#pragma unroll
    for (int j = 0; j < 4; ++j) {
      const int qr = q0 + w * 16 + 4 * hi + j;
      float s = acc[j] * 0.125f;
      int dist = qr - kcol; dist = dist < 0 ? -dist : dist;
      s = (dist <= WIN) ? s : NEGBIG;
      const float mn = fmaxf(m[j], s);
      const float e = __expf(fminf(s - m[j], m[j] - s));   // exp(-|s-m|), 1 transcendental
      l[j] = (s > m[j]) ? (l[j] * e + 1.f) : (l[j] + e);
      m[j] = mn;
    }
    p0 = n0; p1 = n1; p2 = n2; p3 = n3;
  }

  // prefetch first pass-B tile so its latency hides under the lane combine
  { const float* kr = KADDR(2 * s0); LD4(kr, p0, p1, p2, p3); }

  // cross-lane (c-group) combine of (m,l)
#pragma unroll
  for (int j = 0; j < 4; ++j) {
#pragma unroll
    for (int d = 1; d <= 8; d <<= 1) {
      const float mo = __shfl_xor(m[j], d);
      const float lo = __shfl_xor(l[j], d);
      const float mn = fmaxf(m[j], mo);
      l[j] = l[j] * __expf(m[j] - mn) + lo * __expf(mo - mn);
      m[j] = mn;
    }
  }
  float il[4];
#pragma unroll
  for (int j = 0; j < 4; ++j) il[j] = 1.0f / l[j];

  // ---- pass B: recompute per tile, P -> LDS, band stores, PV ----
  char* pw = Pb + w * 1024;
  float* arow = aptr + (size_t)(q0 + w * 16 + c) * T_DIM + kstart;  // lane's band row
  const f32x4 zv = {0.f, 0.f, 0.f, 0.f};
  f32x4 ov[4];
#pragma unroll
  for (int dt = 0; dt < 4; ++dt) ov[dt] = zv;

  for (int kt = 2 * s0; kt < 2 * s1; ++kt) {
    f32x4 n0 = p0, n1 = p1, n2 = p2, n3 = p3;
    if (kt + 1 < 2 * s1) { const float* kr = KADDR(kt + 1); LD4(kr, n0, n1, n2, n3); }
    const bf16x8 b0 = cvt8(p0, p1), b1 = cvt8(p2, p3);
    f32x4 acc = {0.f, 0.f, 0.f, 0.f};
    acc = __builtin_amdgcn_mfma_f32_16x16x32_bf16(a0, b0, acc, 0, 0, 0);
    acc = __builtin_amdgcn_mfma_f32_16x16x32_bf16(a1, b1, acc, 0, 0, 0);
    const int kcol = kstart + kt * 16 + c;
    const int hb = (kt & 1) * 32;
#pragma unroll
    for (int j = 0; j < 4; ++j) {
      const int qr = q0 + w * 16 + 4 * hi + j;
      int dist = qr - kcol; dist = dist < 0 ? -dist : dist;
      const float p = (dist <= WIN) ? __expf(acc[j] * 0.125f - m[j]) * il[j] : 0.f;
      *(short*)(pw + (4 * hi + j) * 64 + ((2 * c + hb) ^ (j << 4))) = f2b(p);
    }
    if (kt & 1) {   // slice complete: emit band + PV
      const int s = kt >> 1;
      const bf16x8 pa = *(const bf16x8*)(pw + c * 64 + ((16 * hi) ^ ((c & 3) << 4)));
      f32x4 o1, o2;
      o1[0] = b2f(pa[0]); o1[1] = b2f(pa[1]); o1[2] = b2f(pa[2]); o1[3] = b2f(pa[3]);
      o2[0] = b2f(pa[4]); o2[1] = b2f(pa[5]); o2[2] = b2f(pa[6]); o2[3] = b2f(pa[7]);
      float* dst = arow + 32 * s + 8 * hi;
      __builtin_nontemporal_store(o1, (f32x4*)dst);
      __builtin_nontemporal_store(o2, (f32x4*)(dst + 4));
#pragma unroll
      for (int dt = 0; dt < 4; ++dt) {
        const bf16x8 vb = *(const bf16x8*)(Vb + swzV(dt * 16 + c, 64 * s + 16 * hi));
        ov[dt] = __builtin_amdgcn_mfma_f32_16x16x32_bf16(pa, vb, ov[dt], 0, 0, 0);
      }
    }
    p0 = n0; p1 = n1; p2 = n2; p3 = n3;
  }

  // dead in-band slices (wave-uniform all-masked) -> zeros; after all loads
  for (int s = 0; s < s0; ++s) {
    float* dst = arow + 32 * s + 8 * hi;
    __builtin_nontemporal_store(zv, (f32x4*)dst);
    __builtin_nontemporal_store(zv, (f32x4*)(dst + 4));
  }
  for (int s = s1; s < ns; ++s) {
    float* dst = arow + 32 * s + 8 * hi;
    __builtin_nontemporal_store(zv, (f32x4*)dst);
    __builtin_nontemporal_store(zv, (f32x4*)(dst + 4));
  }

  // ---- O store ----
#pragma unroll
  for (int dt = 0; dt < 4; ++dt)
#pragma unroll
    for (int j = 0; j < 4; ++j)
      __builtin_nontemporal_store(
          ov[dt][j], optr + (size_t)(q0 + w * 16 + 4 * hi + j) * D_DIM + dt * 16 + c);
}

extern "C" void kernel_launch(void* const* d_in, const int* in_sizes, int n_in,
                              void* d_out, int out_size, void* d_ws, size_t ws_size,
                              hipStream_t stream) {
  const float* q = (const float*)d_in[0];
  const float* k = (const float*)d_in[1];
  const float* v = (const float*)d_in[2];
  float* out = (float*)d_out;
  float* attn = out + (size_t)2 * 16 * T_DIM * D_DIM;  // output first, then attn
  lsa_one<<<dim3(2 * 16 * (T_DIM / QBLK)), dim3(512), 0, stream>>>(q, k, v, out, attn);
}

// Round 6
// 134.348 us; speedup vs baseline: 1.1867x; 1.1867x over previous
//
#include <hip/hip_runtime.h>
#include <hip/hip_bf16.h>

typedef short bf16x8 __attribute__((ext_vector_type(8)));
typedef short bf16x4 __attribute__((ext_vector_type(4)));
typedef float f32x4 __attribute__((ext_vector_type(4)));

#define T_DIM 2048
#define D_DIM 64
#define WIN 128
#define QBLK 64
#define NKT_MAX 20
#define ACCT 17          // max live 16-wide k-tiles per 16-row wave tile: (16+2*128)/16
#define NEGBIG -1e30f

__device__ __forceinline__ short f2b(float x) {
  __hip_bfloat16 h = __float2bfloat16(x);
  return *reinterpret_cast<short*>(&h);
}
__device__ __forceinline__ float b2f(short s) {
  unsigned u = ((unsigned)(unsigned short)s) << 16;
  return __builtin_bit_cast(float, u);
}
__device__ __forceinline__ bf16x8 cvt8(f32x4 a, f32x4 b) {
  bf16x8 r;
  r[0] = f2b(a[0]); r[1] = f2b(a[1]); r[2] = f2b(a[2]); r[3] = f2b(a[3]);
  r[4] = f2b(b[0]); r[5] = f2b(b[1]); r[6] = f2b(b[2]); r[7] = f2b(b[3]);
  return r;
}
// swizzled byte address in a 640B-row LDS tile (Vt rows = d, Pb rows = q)
__device__ __forceinline__ int swz(int row, int b) { return row * 640 + (b ^ ((row & 7) << 4)); }

__global__ __launch_bounds__(256, 2) void lsa_one(
    const float* __restrict__ Qg, const float* __restrict__ Kg,
    const float* __restrict__ Vg, float* __restrict__ Og,
    float* __restrict__ Ag) {
  const int tid = threadIdx.x;
  // XCD-chunked swizzle: XCD x hosts works [128x,128x+128) = 4 bh, 32 q-blocks
  const int work = ((blockIdx.x & 7) << 7) + (blockIdx.x >> 3);
  const int bh = work >> 5;
  const int q0 = (work & 31) * QBLK;
  int kstart = q0 - WIN; if (kstart < 0) kstart = 0;
  int kend = q0 + QBLK + WIN; if (kend > T_DIM) kend = T_DIM;
  const int KW = kend - kstart;   // 192/256/320
  const int nkt = KW >> 4;

  const float* qptr = Qg + (size_t)bh * (T_DIM * D_DIM);
  const float* kptr = Kg + (size_t)bh * (T_DIM * D_DIM);
  const float* vptr = Vg + (size_t)bh * (T_DIM * D_DIM);
  float* optr = Og + (size_t)bh * (T_DIM * D_DIM);
  float* aptr = Ag + (size_t)bh * ((size_t)T_DIM * T_DIM);

  // LDS: Vt 40KB + P band 40KB = 80KB -> 2 blocks/CU
  __shared__ __align__(16) char Vb[D_DIM * 640];
  __shared__ __align__(16) char Pb[QBLK * 640];

  // ---- stage V transposed: Vt[d][k] bf16 ----
  for (int idx = tid; idx < KW * 16; idx += 256) {
    const int r = idx >> 4, c4 = idx & 15;
    f32x4 f = *(const f32x4*)(vptr + (size_t)(kstart + r) * D_DIM + c4 * 4);
    const int d0 = c4 * 4;
    *(short*)(Vb + swz(d0 + 0, r * 2)) = f2b(f[0]);
    *(short*)(Vb + swz(d0 + 1, r * 2)) = f2b(f[1]);
    *(short*)(Vb + swz(d0 + 2, r * 2)) = f2b(f[2]);
    *(short*)(Vb + swz(d0 + 3, r * 2)) = f2b(f[3]);
  }
  __syncthreads();   // only barrier

  const int lane = tid & 63, w = tid >> 6, c = lane & 15, hi = lane >> 4;

  // Q A-frags
  const float* qrow = qptr + (size_t)(q0 + w * 16 + c) * D_DIM + 8 * hi;
  const bf16x8 a0 = cvt8(*(const f32x4*)qrow, *(const f32x4*)(qrow + 4));
  const bf16x8 a1 = cvt8(*(const f32x4*)(qrow + 32), *(const f32x4*)(qrow + 36));

  // per-wave live tile range
  int klo = q0 + w * 16 - WIN - kstart; if (klo < 0) klo = 0;
  const int kt0 = klo >> 4;
  int kt1 = (q0 + w * 16 + 15 + WIN + 1 - kstart + 15) >> 4; if (kt1 > nkt) kt1 = nkt;
  const int s0 = kt0 >> 1, s1 = (kt1 + 1) >> 1;
  const int nlive = kt1 - kt0;

  // ---- one-pass S over live tiles ----
  f32x4 acc[ACCT];
#pragma unroll
  for (int i = 0; i < ACCT; ++i) {
    acc[i] = (f32x4){0.f, 0.f, 0.f, 0.f};
    if (i < nlive) {
      const float* kr = kptr + (size_t)(kstart + (kt0 + i) * 16 + c) * D_DIM + 8 * hi;
      const bf16x8 b0 = cvt8(*(const f32x4*)kr, *(const f32x4*)(kr + 4));
      const bf16x8 b1 = cvt8(*(const f32x4*)(kr + 32), *(const f32x4*)(kr + 36));
      acc[i] = __builtin_amdgcn_mfma_f32_16x16x32_bf16(a0, b0, acc[i], 0, 0, 0);
      acc[i] = __builtin_amdgcn_mfma_f32_16x16x32_bf16(a1, b1, acc[i], 0, 0, 0);
    }
  }

  // ---- softmax + P(bf16) -> Pb ----
  const int kgc = kstart + c;
#pragma unroll
  for (int j = 0; j < 4; ++j) {
    const int qr = q0 + w * 16 + 4 * hi + j;
    const int prow = w * 16 + 4 * hi + j;
    float m = NEGBIG;
#pragma unroll
    for (int i = 0; i < ACCT; ++i)
      if (i < nlive) {
        float s = acc[i][j] * 0.125f;            // 1/sqrt(64)
        const int kcol = kgc + (kt0 + i) * 16;
        int dist = qr - kcol; dist = dist < 0 ? -dist : dist;
        s = (dist <= WIN) ? s : NEGBIG;
        acc[i][j] = s;
        m = fmaxf(m, s);
      }
    m = fmaxf(m, __shfl_xor(m, 1));
    m = fmaxf(m, __shfl_xor(m, 2));
    m = fmaxf(m, __shfl_xor(m, 4));
    m = fmaxf(m, __shfl_xor(m, 8));
    float sum = 0.f;
#pragma unroll
    for (int i = 0; i < ACCT; ++i)
      if (i < nlive) {
        const float p = __expf(acc[i][j] - m);
        acc[i][j] = p;
        sum += p;
      }
    sum += __shfl_xor(sum, 1);
    sum += __shfl_xor(sum, 2);
    sum += __shfl_xor(sum, 4);
    sum += __shfl_xor(sum, 8);
    const float inv = 1.f / sum;
#pragma unroll
    for (int i = 0; i < ACCT; ++i)
      if (i < nlive)
        *(short*)(Pb + swz(prow, ((kt0 + i) * 16 + c) * 2)) = f2b(acc[i][j] * inv);
    // dead tiles of this row -> zero (sweep + PV read full band)
    for (int t = 0; t < kt0; ++t)
      *(short*)(Pb + swz(prow, (t * 16 + c) * 2)) = 0;
    for (int t = kt1; t < nkt; ++t)
      *(short*)(Pb + swz(prow, (t * 16 + c) * 2)) = 0;
  }

  // ---- row sweep: full 8KB rows, zeros + band, perfectly sequential ----
  for (int rr = 0; rr < 16; ++rr) {
    const int r = w * 16 + rr;
    float* dst = aptr + (size_t)(q0 + r) * T_DIM;
#pragma unroll
    for (int i = 0; i < 8; ++i) {
      const int col = i * 256 + lane * 4;
      f32x4 val = {0.f, 0.f, 0.f, 0.f};
      if (col >= kstart && col < kend) {
        const bf16x4 pv = *(const bf16x4*)(Pb + swz(r, (col - kstart) * 2));
        val[0] = b2f(pv[0]); val[1] = b2f(pv[1]); val[2] = b2f(pv[2]); val[3] = b2f(pv[3]);
      }
      __builtin_nontemporal_store(val, (f32x4*)(dst + col));
    }
  }

  // ---- O = P V ----
  f32x4 ov[4];
#pragma unroll
  for (int dt = 0; dt < 4; ++dt) ov[dt] = (f32x4){0.f, 0.f, 0.f, 0.f};
  for (int s = s0; s < s1; ++s) {
    const bf16x8 pa = *(const bf16x8*)(Pb + swz(w * 16 + c, 64 * s + 16 * hi));
#pragma unroll
    for (int dt = 0; dt < 4; ++dt) {
      const bf16x8 vb = *(const bf16x8*)(Vb + swz(dt * 16 + c, 64 * s + 16 * hi));
      ov[dt] = __builtin_amdgcn_mfma_f32_16x16x32_bf16(pa, vb, ov[dt], 0, 0, 0);
    }
  }
#pragma unroll
  for (int dt = 0; dt < 4; ++dt)
#pragma unroll
    for (int j = 0; j < 4; ++j)
      __builtin_nontemporal_store(
          ov[dt][j], optr + (size_t)(q0 + w * 16 + 4 * hi + j) * D_DIM + dt * 16 + c);
}

extern "C" void kernel_launch(void* const* d_in, const int* in_sizes, int n_in,
                              void* d_out, int out_size, void* d_ws, size_t ws_size,
                              hipStream_t stream) {
  const float* q = (const float*)d_in[0];
  const float* k = (const float*)d_in[1];
  const float* v = (const float*)d_in[2];
  float* out = (float*)d_out;
  float* attn = out + (size_t)2 * 16 * T_DIM * D_DIM;  // output first, then attn
  lsa_one<<<dim3(2 * 16 * (T_DIM / QBLK)), dim3(256), 0, stream>>>(q, k, v, out, attn);
}

// Round 7
// 129.001 us; speedup vs baseline: 1.2359x; 1.0415x over previous
//
#include <hip/hip_runtime.h>
#include <hip/hip_bf16.h>

typedef short bf16x8 __attribute__((ext_vector_type(8)));
typedef short bf16x4 __attribute__((ext_vector_type(4)));
typedef float f32x4 __attribute__((ext_vector_type(4)));

#define T_DIM 2048
#define D_DIM 64
#define WIN 128
#define QBLK 64
#define ACCT 17          // max live 16-wide k-tiles per 16-row wave tile: (16+2*128)/16
#define NEGBIG -1e30f

__device__ __forceinline__ short f2b(float x) {
  __hip_bfloat16 h = __float2bfloat16(x);
  return *reinterpret_cast<short*>(&h);
}
__device__ __forceinline__ float b2f(short s) {
  unsigned u = ((unsigned)(unsigned short)s) << 16;
  return __builtin_bit_cast(float, u);
}
__device__ __forceinline__ bf16x8 cvt8(f32x4 a, f32x4 b) {
  bf16x8 r;
  r[0] = f2b(a[0]); r[1] = f2b(a[1]); r[2] = f2b(a[2]); r[3] = f2b(a[3]);
  r[4] = f2b(b[0]); r[5] = f2b(b[1]); r[6] = f2b(b[2]); r[7] = f2b(b[3]);
  return r;
}
// swizzled byte address in a 640B-row LDS tile (Vt rows = d, Pb rows = q)
__device__ __forceinline__ int swz(int row, int b) { return row * 640 + (b ^ ((row & 7) << 4)); }

__global__ __launch_bounds__(256, 2) void lsa_one(
    const float* __restrict__ Qg, const float* __restrict__ Kg,
    const float* __restrict__ Vg, float* __restrict__ Og,
    float* __restrict__ Ag) {
  const int tid = threadIdx.x;
  // XCD-chunked swizzle: XCD x hosts works [128x,128x+128) = 4 bh, 32 q-blocks
  const int work = ((blockIdx.x & 7) << 7) + (blockIdx.x >> 3);
  const int bh = work >> 5;
  const int q0 = (work & 31) * QBLK;
  int kstart = q0 - WIN; if (kstart < 0) kstart = 0;
  int kend = q0 + QBLK + WIN; if (kend > T_DIM) kend = T_DIM;
  const int KW = kend - kstart;   // 192/256/320
  const int nkt = KW >> 4;

  const float* qptr = Qg + (size_t)bh * (T_DIM * D_DIM);
  const float* kptr = Kg + (size_t)bh * (T_DIM * D_DIM);
  const float* vptr = Vg + (size_t)bh * (T_DIM * D_DIM);
  float* optr = Og + (size_t)bh * (T_DIM * D_DIM);
  float* aptr = Ag + (size_t)bh * ((size_t)T_DIM * T_DIM);

  // LDS: Vt 40KB + P band 40KB = 80KB -> 2 blocks/CU
  __shared__ __align__(16) char Vb[D_DIM * 640];
  __shared__ __align__(16) char Pb[QBLK * 640];

  // ---- stage V transposed: Vt[d][k] bf16 (no barrier yet; consumed by PV) ----
  for (int idx = tid; idx < KW * 16; idx += 256) {
    const int r = idx >> 4, c4 = idx & 15;
    f32x4 f = *(const f32x4*)(vptr + (size_t)(kstart + r) * D_DIM + c4 * 4);
    const int d0 = c4 * 4;
    *(short*)(Vb + swz(d0 + 0, r * 2)) = f2b(f[0]);
    *(short*)(Vb + swz(d0 + 1, r * 2)) = f2b(f[1]);
    *(short*)(Vb + swz(d0 + 2, r * 2)) = f2b(f[2]);
    *(short*)(Vb + swz(d0 + 3, r * 2)) = f2b(f[3]);
  }

  const int lane = tid & 63, w = tid >> 6, c = lane & 15, hi = lane >> 4;

  // Q B-frag (swapped QK^T): lane holds Q row q0+w*16+c, d-slices
  const float* qrow = qptr + (size_t)(q0 + w * 16 + c) * D_DIM + 8 * hi;
  const bf16x8 qb0 = cvt8(*(const f32x4*)qrow, *(const f32x4*)(qrow + 4));
  const bf16x8 qb1 = cvt8(*(const f32x4*)(qrow + 32), *(const f32x4*)(qrow + 36));

  // per-wave live tile range
  int klo = q0 + w * 16 - WIN - kstart; if (klo < 0) klo = 0;
  const int kt0 = klo >> 4;
  int kt1 = (q0 + w * 16 + 15 + WIN + 1 - kstart + 15) >> 4; if (kt1 > nkt) kt1 = nkt;
  const int s0 = kt0 >> 1, s1 = (kt1 + 1) >> 1;
  const int nlive = kt1 - kt0;

  // ---- S^T = K Q^T over live tiles: lane (c,hi) owns q-row c, k = 16i+4hi+j ----
  f32x4 acc[ACCT];
#pragma unroll
  for (int i = 0; i < ACCT; ++i) {
    acc[i] = (f32x4){0.f, 0.f, 0.f, 0.f};
    if (i < nlive) {
      const float* kr = kptr + (size_t)(kstart + (kt0 + i) * 16 + c) * D_DIM + 8 * hi;
      const bf16x8 b0 = cvt8(*(const f32x4*)kr, *(const f32x4*)(kr + 4));
      const bf16x8 b1 = cvt8(*(const f32x4*)(kr + 32), *(const f32x4*)(kr + 36));
      acc[i] = __builtin_amdgcn_mfma_f32_16x16x32_bf16(b0, qb0, acc[i], 0, 0, 0);
      acc[i] = __builtin_amdgcn_mfma_f32_16x16x32_bf16(b1, qb1, acc[i], 0, 0, 0);
    }
  }

  // ---- softmax: in-lane over 68 values, then 2 shfls across hi-groups ----
  const int qr = q0 + w * 16 + c;            // this lane's q-row
  const int kb = kstart + 4 * hi;
  float m = NEGBIG;
#pragma unroll
  for (int i = 0; i < ACCT; ++i)
    if (i < nlive) {
#pragma unroll
      for (int j = 0; j < 4; ++j) {
        float s = acc[i][j] * 0.125f;        // 1/sqrt(64)
        const int kcol = kb + (kt0 + i) * 16 + j;
        int dist = qr - kcol; dist = dist < 0 ? -dist : dist;
        s = (dist <= WIN) ? s : NEGBIG;
        acc[i][j] = s;
        m = fmaxf(m, s);
      }
    }
  m = fmaxf(m, __shfl_xor(m, 16));
  m = fmaxf(m, __shfl_xor(m, 32));
  float sum = 0.f;
#pragma unroll
  for (int i = 0; i < ACCT; ++i)
    if (i < nlive) {
#pragma unroll
      for (int j = 0; j < 4; ++j) {
        const float p = __expf(acc[i][j] - m);
        acc[i][j] = p;
        sum += p;
      }
    }
  sum += __shfl_xor(sum, 16);
  sum += __shfl_xor(sum, 32);
  const float inv = 1.f / sum;

  // ---- P(bf16) -> Pb: one ds_write_b64 per live tile ----
  const int prow = w * 16 + c;
#pragma unroll
  for (int i = 0; i < ACCT; ++i)
    if (i < nlive) {
      bf16x4 pk;
#pragma unroll
      for (int j = 0; j < 4; ++j) pk[j] = f2b(acc[i][j] * inv);
      *(bf16x4*)(Pb + swz(prow, 32 * (kt0 + i) + 8 * hi)) = pk;
    }
  {
    const bf16x4 z4 = {0, 0, 0, 0};
    for (int t = 0; t < kt0; ++t) *(bf16x4*)(Pb + swz(prow, 32 * t + 8 * hi)) = z4;
    for (int t = kt1; t < nkt; ++t) *(bf16x4*)(Pb + swz(prow, 32 * t + 8 * hi)) = z4;
  }

  // ---- row sweep: full 8KB rows, zeros + band, perfectly sequential ----
  for (int rr = 0; rr < 16; ++rr) {
    const int r = w * 16 + rr;
    float* dst = aptr + (size_t)(q0 + r) * T_DIM;
#pragma unroll
    for (int i = 0; i < 8; ++i) {
      const int col = i * 256 + lane * 4;
      f32x4 val = {0.f, 0.f, 0.f, 0.f};
      if (col >= kstart && col < kend) {
        const bf16x4 pv = *(const bf16x4*)(Pb + swz(r, (col - kstart) * 2));
        val[0] = b2f(pv[0]); val[1] = b2f(pv[1]); val[2] = b2f(pv[2]); val[3] = b2f(pv[3]);
      }
      __builtin_nontemporal_store(val, (f32x4*)(dst + col));
    }
  }

  __syncthreads();   // only barrier: Vt ready for PV

  // ---- O = P V ----
  f32x4 ov[4];
#pragma unroll
  for (int dt = 0; dt < 4; ++dt) ov[dt] = (f32x4){0.f, 0.f, 0.f, 0.f};
  for (int s = s0; s < s1; ++s) {
    const bf16x8 pa = *(const bf16x8*)(Pb + swz(w * 16 + c, 64 * s + 16 * hi));
#pragma unroll
    for (int dt = 0; dt < 4; ++dt) {
      const bf16x8 vb = *(const bf16x8*)(Vb + swz(dt * 16 + c, 64 * s + 16 * hi));
      ov[dt] = __builtin_amdgcn_mfma_f32_16x16x32_bf16(pa, vb, ov[dt], 0, 0, 0);
    }
  }
#pragma unroll
  for (int dt = 0; dt < 4; ++dt)
#pragma unroll
    for (int j = 0; j < 4; ++j)
      __builtin_nontemporal_store(
          ov[dt][j], optr + (size_t)(q0 + w * 16 + 4 * hi + j) * D_DIM + dt * 16 + c);
}

extern "C" void kernel_launch(void* const* d_in, const int* in_sizes, int n_in,
                              void* d_out, int out_size, void* d_ws, size_t ws_size,
                              hipStream_t stream) {
  const float* q = (const float*)d_in[0];
  const float* k = (const float*)d_in[1];
  const float* v = (const float*)d_in[2];
  float* out = (float*)d_out;
  float* attn = out + (size_t)2 * 16 * T_DIM * D_DIM;  // output first, then attn
  lsa_one<<<dim3(2 * 16 * (T_DIM / QBLK)), dim3(256), 0, stream>>>(q, k, v, out, attn);
}